// Round 7
// baseline (824.909 us; speedup 1.0000x reference)
//
#include <hip/hip_runtime.h>
#include <stdint.h>

typedef unsigned short u16;

#define E_    8
#define DIM_  1024
#define HID_  2048
#define H2_   4096     // 2*HID
#define NTOK  8192     // B*T
#define RTOK  32       // tokens per router block
#define NT1   16       // K-tiles gemm1 (1024/64)
#define NT2   32       // K-tiles gemm2 (2048/64)

typedef __attribute__((ext_vector_type(8))) short bf16x8;
typedef __attribute__((ext_vector_type(4))) float f32x4;
typedef __attribute__((ext_vector_type(4))) unsigned int u32x4;

__device__ __forceinline__ u16 f2bf(float f) {
  uint32_t u = __builtin_bit_cast(uint32_t, f);
  uint32_t r = (u + 0x7FFFu + ((u >> 16) & 1u)) >> 16;
  return (u16)r;
}
__device__ __forceinline__ float bf2f(u16 u) {
  return __builtin_bit_cast(float, (uint32_t)u << 16);
}

__device__ __forceinline__ void gload16(const void* g, void* l) {
  __builtin_amdgcn_global_load_lds(
      (const __attribute__((address_space(1))) void*)g,
      (__attribute__((address_space(3))) void*)l, 16, 0, 0);
}

// LDS byte address (AS3, 32-bit) for inline-asm DS ops
__device__ __forceinline__ uint32_t lds_addr(const void* p) {
  return (uint32_t)(uintptr_t)(const __attribute__((address_space(3))) void*)p;
}
// Opaque ds_read_b128: compiler cannot see an LDS read -> no auto vmcnt drain.
__device__ __forceinline__ bf16x8 ldsr(uint32_t a) {
  u32x4 r;
  asm volatile("ds_read_b128 %0, %1" : "=v"(r) : "v"(a));
  return __builtin_bit_cast(bf16x8, r);
}

#define MFMA_ __builtin_amdgcn_mfma_f32_16x16x32_bf16
#define SB0   __builtin_amdgcn_sched_barrier(0)
#define BAR   __builtin_amdgcn_s_barrier

// ---------------- conversion kernels ----------------

__global__ void cvt_x(const float* __restrict__ x, u16* __restrict__ xb, int n8) {
  int i = blockIdx.x * blockDim.x + threadIdx.x;
  if (i >= n8) return;
  const float4* p = (const float4*)(x + (size_t)i * 8);
  float4 a = p[0], b = p[1];
  union { u16 u[8]; uint4 v; } r;
  r.u[0] = f2bf(a.x); r.u[1] = f2bf(a.y); r.u[2] = f2bf(a.z); r.u[3] = f2bf(a.w);
  r.u[4] = f2bf(b.x); r.u[5] = f2bf(b.y); r.u[6] = f2bf(b.z); r.u[7] = f2bf(b.w);
  *(uint4*)(xb + (size_t)i * 8) = r.v;
}

// src [e][R][C] fp32 -> dst [e][C][R] bf16 (32x32 tiles)
__global__ void tconv(const float* __restrict__ src, u16* __restrict__ dst, int R, int C) {
  __shared__ float t[32][33];
  int e = blockIdx.z;
  int r0 = blockIdx.y * 32, c0 = blockIdx.x * 32;
  const float* s = src + (size_t)e * R * C;
  u16* d = dst + (size_t)e * R * C;
  int tid = threadIdx.x;
  int rr = tid >> 3, cc = (tid & 7) * 4;
  float4 v = *(const float4*)(s + (size_t)(r0 + rr) * C + c0 + cc);
  t[rr][cc + 0] = v.x; t[rr][cc + 1] = v.y; t[rr][cc + 2] = v.z; t[rr][cc + 3] = v.w;
  __syncthreads();
  ushort4 w;
  w.x = f2bf(t[cc + 0][rr]);
  w.y = f2bf(t[cc + 1][rr]);
  w.z = f2bf(t[cc + 2][rr]);
  w.w = f2bf(t[cc + 3][rr]);
  *(ushort4*)(d + (size_t)(c0 + rr) * R + r0 + cc) = w;
}

// ---------------- router (block-aggregated, low-contention atomics) ----------------

__global__ void router(const float* __restrict__ x, const float* __restrict__ rw,
                       const float* __restrict__ rb, int* __restrict__ counts,
                       int* __restrict__ btok, float* __restrict__ bw,
                       int* __restrict__ tokrec) {
  __shared__ float srw[E_ * DIM_];
  __shared__ float sb[E_];
  __shared__ int   hcnt[E_], hbase[E_];
  __shared__ int   te[RTOK * 2];
  __shared__ float twt[RTOK * 2];
  __shared__ int   tloc[RTOK * 2];

  int tid = threadIdx.x;
  for (int i = tid; i < E_ * DIM_ / 4; i += 256)
    ((float4*)srw)[i] = ((const float4*)rw)[i];
  if (tid < E_) { sb[tid] = rb[tid]; hcnt[tid] = 0; }
  __syncthreads();

  int wid = tid >> 6, lane = tid & 63;
#pragma unroll
  for (int s = 0; s < RTOK / 4; ++s) {
    int lt = wid * (RTOK / 4) + s;
    int t = blockIdx.x * RTOK + lt;
    const float* xt = x + (size_t)t * DIM_;
    float acc[8] = {0.f, 0.f, 0.f, 0.f, 0.f, 0.f, 0.f, 0.f};
#pragma unroll
    for (int it = 0; it < 4; ++it) {
      int d = it * 256 + lane * 4;
      float4 xv = *(const float4*)(xt + d);
#pragma unroll
      for (int e = 0; e < 8; ++e) {
        float4 rv = *(const float4*)(&srw[e * DIM_ + d]);
        acc[e] += xv.x * rv.x + xv.y * rv.y + xv.z * rv.z + xv.w * rv.w;
      }
    }
#pragma unroll
    for (int e = 0; e < 8; ++e)
#pragma unroll
      for (int off = 32; off; off >>= 1)
        acc[e] += __shfl_xor(acc[e], off, 64);
    if (lane == 0) {
      float v[8];
#pragma unroll
      for (int e = 0; e < 8; ++e) v[e] = acc[e] + sb[e];
      int i0 = 0;
#pragma unroll
      for (int e = 1; e < 8; ++e) if (v[e] > v[i0]) i0 = e;
      int i1 = (i0 == 0) ? 1 : 0;
#pragma unroll
      for (int e = 0; e < 8; ++e) if (e != i0 && v[e] > v[i1]) i1 = e;
      float w0 = 1.f / (1.f + expf(v[i1] - v[i0]));
      float w1 = 1.f - w0;
      int l0 = atomicAdd(&hcnt[i0], 1);
      int l1 = atomicAdd(&hcnt[i1], 1);
      te[lt * 2 + 0] = i0; twt[lt * 2 + 0] = w0; tloc[lt * 2 + 0] = l0;
      te[lt * 2 + 1] = i1; twt[lt * 2 + 1] = w1; tloc[lt * 2 + 1] = l1;
    }
  }
  __syncthreads();
  if (tid < E_) hbase[tid] = atomicAdd(&counts[tid], hcnt[tid]);
  __syncthreads();
  if (tid < RTOK * 2) {
    int e = te[tid];
    int p = hbase[e] + tloc[tid];
    int t = blockIdx.x * RTOK + (tid >> 1);
    btok[e * NTOK + p] = t;
    bw[e * NTOK + p] = twt[tid];
    tokrec[t * 2 + (tid & 1)] = (e << 13) | p;
  }
}

// ================= 256x256 8-phase GEMM core =================
// 512 thr = 8 waves (2M x 4N), BK=64, double-buffered 128 KiB LDS.
// All K-loop LDS reads are inline-asm ds_read_b128 (invisible to the
// compiler's waitcnt insertion) so the counted vmcnt(4) pipeline survives.
// lgkmcnt ladder at phase 0 pipelines the 18-read burst into the MFMAs.

#define STG2(sm_, pArr, buf, reg, half, tile, NTt)                         \
  {                                                                        \
    int tc_ = (tile) < (NTt) ? (tile) : (NTt)-1;                           \
    u16* d_ = (sm_) + (buf)*32768 + (reg)*16384 + (half)*8192 + wid * 512; \
    gload16(pArr[(half)*2 + 0] + tc_ * 64, d_);                            \
    gload16(pArr[(half)*2 + 1] + tc_ * 64, d_ + 4096);                     \
  }

template <int NTt>
__device__ __forceinline__ void kloop(u16* __restrict__ sm,
                                      const u16* const* pA, const u16* const* pB,
                                      int wid, int wr, int wc, int l15, int lhi,
                                      int rxor, f32x4 (&acc)[8][4]) {
  // prologue: tile0 A+B, tile1 A  (12 loads)
  STG2(sm, pA, 0, 0, 0, 0, NTt); STG2(sm, pA, 0, 0, 1, 0, NTt);
  STG2(sm, pB, 0, 1, 0, 0, NTt); STG2(sm, pB, 0, 1, 1, 0, NTt);
  STG2(sm, pA, 1, 0, 0, 1, NTt); STG2(sm, pA, 1, 0, 1, 1, NTt);
  asm volatile("s_waitcnt vmcnt(4)" ::: "memory");
  BAR();

  const uint32_t k0 = (uint32_t)(((lhi * 8) ^ rxor) * 2);        // byte offs
  const uint32_t k1 = (uint32_t)((((4 + lhi) * 8) ^ rxor) * 2);

  for (int i = 0; i < NTt / 2; ++i) {
    int t2 = 2 * i;
#pragma unroll
    for (int h = 0; h < 2; ++h) {
      uint32_t aB = lds_addr(sm) + (uint32_t)(h * 65536) +
                    (uint32_t)((wr * 128 + l15) * 128);
      uint32_t bB = lds_addr(sm) + (uint32_t)(h * 65536 + 32768) +
                    (uint32_t)((wc * 64 + l15) * 128);

      // ---- phase 0 (quadrant q=0): issue b0,b1 then a[0..7][0..1] ----
      bf16x8 b0 = ldsr(bB + k0);
      bf16x8 b1 = ldsr(bB + k1);
      bf16x8 a[8][2];
#pragma unroll
      for (int m = 0; m < 8; ++m) {
        a[m][0] = ldsr(aB + (uint32_t)(m * 2048) + k0);
        a[m][1] = ldsr(aB + (uint32_t)(m * 2048) + k1);
      }
      if (h == 0) STG2(sm, pB, 1, 1, 0, t2 + 1, NTt)
      else        STG2(sm, pB, 0, 1, 0, t2 + 2, NTt)
      BAR();
      __builtin_amdgcn_s_setprio(1);
      asm volatile("s_waitcnt lgkmcnt(12)");
      SB0;
      acc[0][0] = MFMA_(a[0][0], b0, acc[0][0], 0, 0, 0);
      acc[0][0] = MFMA_(a[0][1], b1, acc[0][0], 0, 0, 0);
      acc[1][0] = MFMA_(a[1][0], b0, acc[1][0], 0, 0, 0);
      acc[1][0] = MFMA_(a[1][1], b1, acc[1][0], 0, 0, 0);
      asm volatile("s_waitcnt lgkmcnt(8)");
      SB0;
      acc[2][0] = MFMA_(a[2][0], b0, acc[2][0], 0, 0, 0);
      acc[2][0] = MFMA_(a[2][1], b1, acc[2][0], 0, 0, 0);
      acc[3][0] = MFMA_(a[3][0], b0, acc[3][0], 0, 0, 0);
      acc[3][0] = MFMA_(a[3][1], b1, acc[3][0], 0, 0, 0);
      asm volatile("s_waitcnt lgkmcnt(4)");
      SB0;
      acc[4][0] = MFMA_(a[4][0], b0, acc[4][0], 0, 0, 0);
      acc[4][0] = MFMA_(a[4][1], b1, acc[4][0], 0, 0, 0);
      acc[5][0] = MFMA_(a[5][0], b0, acc[5][0], 0, 0, 0);
      acc[5][0] = MFMA_(a[5][1], b1, acc[5][0], 0, 0, 0);
      asm volatile("s_waitcnt lgkmcnt(0)");
      SB0;
      acc[6][0] = MFMA_(a[6][0], b0, acc[6][0], 0, 0, 0);
      acc[6][0] = MFMA_(a[6][1], b1, acc[6][0], 0, 0, 0);
      acc[7][0] = MFMA_(a[7][0], b0, acc[7][0], 0, 0, 0);
      acc[7][0] = MFMA_(a[7][1], b1, acc[7][0], 0, 0, 0);
      __builtin_amdgcn_s_setprio(0);
      BAR();

      // ---- phases q=1..3 ----
#pragma unroll
      for (int q = 1; q < 4; ++q) {
        bf16x8 c0 = ldsr(bB + (uint32_t)(q * 2048) + k0);
        bf16x8 c1 = ldsr(bB + (uint32_t)(q * 2048) + k1);
        if (h == 0) {
          if (q == 1)      STG2(sm, pB, 1, 1, 1, t2 + 1, NTt)
          else if (q == 2) STG2(sm, pA, 0, 0, 0, t2 + 2, NTt)
          else             STG2(sm, pA, 0, 0, 1, t2 + 2, NTt)
        } else {
          if (q == 1)      STG2(sm, pB, 0, 1, 1, t2 + 2, NTt)
          else if (q == 2) STG2(sm, pA, 1, 0, 0, t2 + 3, NTt)
          else             STG2(sm, pA, 1, 0, 1, t2 + 3, NTt)
        }
        BAR();
        asm volatile("s_waitcnt lgkmcnt(0)");
        SB0;
        __builtin_amdgcn_s_setprio(1);
#pragma unroll
        for (int m = 0; m < 8; ++m) {
          acc[m][q] = MFMA_(a[m][0], c0, acc[m][q], 0, 0, 0);
          acc[m][q] = MFMA_(a[m][1], c1, acc[m][q], 0, 0, 0);
        }
        __builtin_amdgcn_s_setprio(0);
        if (q == 3) asm volatile("s_waitcnt vmcnt(4)" ::: "memory");
        BAR();
      }
    }
  }
  asm volatile("s_waitcnt vmcnt(0)" ::: "memory");
}

// ---------------- GEMM1: gathered x @ W1 -> swiglu -> hb ----------------

__launch_bounds__(512, 2)
__global__ void gemm1(const u16* __restrict__ xb, const u16* __restrict__ w1t,
                      const float* __restrict__ b1, const int* __restrict__ counts,
                      const int* __restrict__ btok, u16* __restrict__ hb) {
  int e = blockIdx.z, mblk = blockIdx.y, nblk = blockIdx.x;
  int cnt = counts[e];
  if (mblk * 256 >= cnt) return;
  int base = 0;
#pragma unroll
  for (int i = 0; i < 8; ++i) base += (i < e) ? counts[i] : 0;

  __shared__ u16 sm[65536];
  __shared__ int sTok[256];

  int tid = threadIdx.x, wid = tid >> 6, lane = tid & 63;
  if (tid < 256) {
    int gr = mblk * 256 + tid;
    sTok[tid] = (gr < cnt) ? btok[e * NTOK + gr] : btok[e * NTOK];
  }
  __syncthreads();

  int wr = wid >> 2, wc = wid & 3;
  int l15 = lane & 15, lhi = lane >> 4;
  int rxor = (l15 & 7) * 8;
  int segsw = ((tid & 7) ^ ((tid >> 3) & 7)) * 8;
  int rowi = tid >> 3;

  const u16* pA[4];
  const u16* pB[4];
  const size_t w1e = (size_t)e * H2_ * DIM_;
#pragma unroll
  for (int j = 0; j < 4; ++j) {
    int r = j * 64 + rowi;
    pA[j] = xb + (size_t)sTok[r] * DIM_ + segsw;
    int gcol = nblk * 128 + j * 32 + (rowi & 31) + ((rowi >> 5) & 1) * 2048;
    pB[j] = w1t + w1e + (size_t)gcol * DIM_ + segsw;
  }

  f32x4 acc[8][4] = {};
  kloop<NT1>(sm, pA, pB, wid, wr, wc, l15, lhi, rxor, acc);

#pragma unroll
  for (int q = 0; q < 2; ++q) {
    int oc = nblk * 128 + wc * 32 + q * 16 + l15;
    float bb1 = b1[e * H2_ + oc];
    float bb2 = b1[e * H2_ + oc + HID_];
#pragma unroll
    for (int m = 0; m < 8; ++m) {
#pragma unroll
      for (int j = 0; j < 4; ++j) {
        int rt = wr * 128 + m * 16 + lhi * 4 + j;
        int gr = mblk * 256 + rt;
        if (gr < cnt) {
          float h1 = acc[m][q][j] + bb1;
          float h2 = acc[m][q + 2][j] + bb2;
          float s = (h1 / (1.f + __expf(-h1))) * h2;
          hb[(size_t)(base + gr) * HID_ + oc] = f2bf(s);
        }
      }
    }
  }
}

// ---------------- GEMM2: hb @ W2 -> w*(y+b2) stored bf16 to ybuf ----------------

__launch_bounds__(512, 2)
__global__ void gemm2(const u16* __restrict__ hb, const u16* __restrict__ w2t,
                      const float* __restrict__ b2, const int* __restrict__ counts,
                      const float* __restrict__ bw, u16* __restrict__ ybuf) {
  int e = blockIdx.z, mblk = blockIdx.y, nblk = blockIdx.x;
  int cnt = counts[e];
  if (mblk * 256 >= cnt) return;
  int base = 0;
#pragma unroll
  for (int i = 0; i < 8; ++i) base += (i < e) ? counts[i] : 0;

  __shared__ u16 sm[65536];
  __shared__ float sW[256];

  int tid = threadIdx.x, wid = tid >> 6, lane = tid & 63;
  if (tid < 256) {
    int gr = mblk * 256 + tid;
    sW[tid] = (gr < cnt) ? bw[e * NTOK + gr] : 0.f;
  }
  __syncthreads();

  int wr = wid >> 2, wc = wid & 3;
  int l15 = lane & 15, lhi = lane >> 4;
  int rxor = (l15 & 7) * 8;
  int segsw = ((tid & 7) ^ ((tid >> 3) & 7)) * 8;
  int rowi = tid >> 3;

  const u16* pA[4];
  const u16* pB[4];
#pragma unroll
  for (int j = 0; j < 4; ++j) {
    pA[j] = hb + (size_t)(base + mblk * 256 + j * 64 + rowi) * HID_ + segsw;
    pB[j] = w2t + (size_t)e * DIM_ * HID_ +
            (size_t)(nblk * 256 + j * 64 + rowi) * HID_ + segsw;
  }

  f32x4 acc[8][4] = {};
  kloop<NT2>(sm, pA, pB, wid, wr, wc, l15, lhi, rxor, acc);

#pragma unroll
  for (int q = 0; q < 4; ++q) {
    int col = nblk * 256 + wc * 64 + q * 16 + l15;
    float bb = b2[e * DIM_ + col];
#pragma unroll
    for (int m = 0; m < 8; ++m) {
#pragma unroll
      for (int j = 0; j < 4; ++j) {
        int rt = wr * 128 + m * 16 + lhi * 4 + j;
        int gr = mblk * 256 + rt;
        if (gr < cnt)
          ybuf[(size_t)(base + gr) * DIM_ + col] = f2bf(sW[rt] * (acc[m][q][j] + bb));
      }
    }
  }
}

// ---------------- combine: out[t] = ybuf[slot(t,0)] + ybuf[slot(t,1)] ----------------

__global__ void combine(const u16* __restrict__ ybuf, const int* __restrict__ tokrec,
                        const int* __restrict__ counts, float* __restrict__ out) {
  __shared__ int sbase[8];
  int tid = threadIdx.x;
  if (tid == 0) {
    int b = 0;
#pragma unroll
    for (int e = 0; e < 8; ++e) { sbase[e] = b; b += counts[e]; }
  }
  __syncthreads();
  int t = blockIdx.x;
  int r0 = tokrec[t * 2 + 0], r1 = tokrec[t * 2 + 1];
  size_t s0 = (size_t)(sbase[r0 >> 13] + (r0 & 8191)) * DIM_;
  size_t s1 = (size_t)(sbase[r1 >> 13] + (r1 & 8191)) * DIM_;
  int c = tid * 4;
  ushort4 a = *(const ushort4*)(ybuf + s0 + c);
  ushort4 b = *(const ushort4*)(ybuf + s1 + c);
  float4 o;
  o.x = bf2f(a.x) + bf2f(b.x);
  o.y = bf2f(a.y) + bf2f(b.y);
  o.z = bf2f(a.z) + bf2f(b.z);
  o.w = bf2f(a.w) + bf2f(b.w);
  *(float4*)(out + (size_t)t * DIM_ + c) = o;
}

// ---------------- launch ----------------

extern "C" void kernel_launch(void* const* d_in, const int* in_sizes, int n_in,
                              void* d_out, int out_size, void* d_ws, size_t ws_size,
                              hipStream_t stream) {
  const float* x  = (const float*)d_in[0];
  const float* rw = (const float*)d_in[1];
  const float* rb = (const float*)d_in[2];
  const float* W1 = (const float*)d_in[3];
  const float* b1 = (const float*)d_in[4];
  const float* W2 = (const float*)d_in[5];
  const float* b2 = (const float*)d_in[6];
  float* out = (float*)d_out;

  char* ws = (char*)d_ws;
  int*   counts = (int*)ws;                         // 32 B (256 pad)
  int*   btok   = (int*)(ws + 256);                 // 256 KB
  float* bw     = (float*)(ws + 256 + 262144);      // 256 KB
  int*   tokrec = (int*)(ws + 256 + 524288);        // 64 KB
  u16* xb  = (u16*)(ws + (1u << 20));               // 16 MB
  u16* w1t = xb  + (size_t)NTOK * DIM_;             // 64 MB
  u16* w2t = w1t + (size_t)E_ * H2_ * DIM_;         // 32 MB
  u16* hb  = w2t + (size_t)E_ * DIM_ * HID_;        // (16384+256)*2048*2 B
  u16* ybuf = w1t;  // alias: w1t dead after gemm1

  hipMemsetAsync(counts, 0, 8 * sizeof(int), stream);

  cvt_x<<<(NTOK * DIM_ / 8 + 255) / 256, 256, 0, stream>>>(x, xb, NTOK * DIM_ / 8);
  tconv<<<dim3(H2_ / 32, DIM_ / 32, E_), 256, 0, stream>>>(W1, w1t, DIM_, H2_);
  tconv<<<dim3(DIM_ / 32, HID_ / 32, E_), 256, 0, stream>>>(W2, w2t, HID_, DIM_);
  router<<<NTOK / RTOK, 256, 0, stream>>>(x, rw, rb, counts, btok, bw, tokrec);

  gemm1<<<dim3(H2_ / 256, NTOK / 256, E_), 512, 0, stream>>>(xb, w1t, b1, counts, btok, hb);
  gemm2<<<dim3(DIM_ / 256, NTOK / 256, E_), 512, 0, stream>>>(hb, w2t, b2, counts, bw, ybuf);
  combine<<<NTOK, 256, 0, stream>>>(ybuf, tokrec, counts, out);
}

// Round 8
// 447.889 us; speedup vs baseline: 1.8418x; 1.8418x over previous
//
#include <hip/hip_runtime.h>
#include <stdint.h>

typedef unsigned short u16;

#define E_    8
#define DIM_  1024
#define HID_  2048
#define H2_   4096     // 2*HID
#define NTOK  8192     // B*T
#define RTOK  32       // tokens per router block
#define NT1   16       // K-tiles gemm1 (1024/64)
#define NT2   32       // K-tiles gemm2 (2048/64)

typedef __attribute__((ext_vector_type(8))) short bf16x8;
typedef __attribute__((ext_vector_type(4))) float f32x4;
typedef __attribute__((ext_vector_type(4))) unsigned int u32x4;

__device__ __forceinline__ u16 f2bf(float f) {
  uint32_t u = __builtin_bit_cast(uint32_t, f);
  uint32_t r = (u + 0x7FFFu + ((u >> 16) & 1u)) >> 16;
  return (u16)r;
}
__device__ __forceinline__ float bf2f(u16 u) {
  return __builtin_bit_cast(float, (uint32_t)u << 16);
}

__device__ __forceinline__ void gload16(const void* g, void* l) {
  __builtin_amdgcn_global_load_lds(
      (const __attribute__((address_space(1))) void*)g,
      (__attribute__((address_space(3))) void*)l, 16, 0, 0);
}

__device__ __forceinline__ uint32_t lds_addr(const void* p) {
  return (uint32_t)(uintptr_t)(const __attribute__((address_space(3))) void*)p;
}
// Opaque ds_read_b128: compiler sees no LDS read -> no auto waitcnt drains.
__device__ __forceinline__ bf16x8 ldsr(uint32_t a) {
  u32x4 r;
  asm volatile("ds_read_b128 %0, %1" : "=v"(r) : "v"(a));
  return __builtin_bit_cast(bf16x8, r);
}

#define MFMA_ __builtin_amdgcn_mfma_f32_16x16x32_bf16
#define SB0   __builtin_amdgcn_sched_barrier(0)

// ---------------- conversion kernels ----------------

__global__ void cvt_x(const float* __restrict__ x, u16* __restrict__ xb, int n8) {
  int i = blockIdx.x * blockDim.x + threadIdx.x;
  if (i >= n8) return;
  const float4* p = (const float4*)(x + (size_t)i * 8);
  float4 a = p[0], b = p[1];
  union { u16 u[8]; uint4 v; } r;
  r.u[0] = f2bf(a.x); r.u[1] = f2bf(a.y); r.u[2] = f2bf(a.z); r.u[3] = f2bf(a.w);
  r.u[4] = f2bf(b.x); r.u[5] = f2bf(b.y); r.u[6] = f2bf(b.z); r.u[7] = f2bf(b.w);
  *(uint4*)(xb + (size_t)i * 8) = r.v;
}

// src [e][R][C] fp32 -> dst [e][C][R] bf16 (64x64 tiles, 128B write granule)
__global__ void tconv(const float* __restrict__ src, u16* __restrict__ dst, int R, int C) {
  __shared__ float t[64][65];
  int e = blockIdx.z;
  int r0 = blockIdx.y * 64, c0 = blockIdx.x * 64;
  const float* s = src + (size_t)e * R * C;
  u16* d = dst + (size_t)e * R * C;
  int tid = threadIdx.x;
  int rr = tid >> 4, cc = (tid & 15) * 4;
#pragma unroll
  for (int p = 0; p < 4; ++p) {
    float4 v = *(const float4*)(s + (size_t)(r0 + p * 16 + rr) * C + c0 + cc);
    t[p * 16 + rr][cc + 0] = v.x; t[p * 16 + rr][cc + 1] = v.y;
    t[p * 16 + rr][cc + 2] = v.z; t[p * 16 + rr][cc + 3] = v.w;
  }
  __syncthreads();
  int cr = tid >> 3, rc = (tid & 7) * 8;
#pragma unroll
  for (int p = 0; p < 2; ++p) {
    union { u16 u[8]; uint4 v; } w;
#pragma unroll
    for (int j = 0; j < 8; ++j) w.u[j] = f2bf(t[rc + j][p * 32 + cr]);
    *(uint4*)(d + (size_t)(c0 + p * 32 + cr) * R + r0 + rc) = w.v;
  }
}

// ---------------- router (block-aggregated, low-contention atomics) ----------------

__global__ void router(const float* __restrict__ x, const float* __restrict__ rw,
                       const float* __restrict__ rb, int* __restrict__ counts,
                       int* __restrict__ btok, float* __restrict__ bw,
                       int* __restrict__ tokrec) {
  __shared__ float srw[E_ * DIM_];
  __shared__ float sb[E_];
  __shared__ int   hcnt[E_], hbase[E_];
  __shared__ int   te[RTOK * 2];
  __shared__ float twt[RTOK * 2];
  __shared__ int   tloc[RTOK * 2];

  int tid = threadIdx.x;
  for (int i = tid; i < E_ * DIM_ / 4; i += 256)
    ((float4*)srw)[i] = ((const float4*)rw)[i];
  if (tid < E_) { sb[tid] = rb[tid]; hcnt[tid] = 0; }
  __syncthreads();

  int wid = tid >> 6, lane = tid & 63;
#pragma unroll
  for (int s = 0; s < RTOK / 4; ++s) {
    int lt = wid * (RTOK / 4) + s;
    int t = blockIdx.x * RTOK + lt;
    const float* xt = x + (size_t)t * DIM_;
    float acc[8] = {0.f, 0.f, 0.f, 0.f, 0.f, 0.f, 0.f, 0.f};
#pragma unroll
    for (int it = 0; it < 4; ++it) {
      int d = it * 256 + lane * 4;
      float4 xv = *(const float4*)(xt + d);
#pragma unroll
      for (int e = 0; e < 8; ++e) {
        float4 rv = *(const float4*)(&srw[e * DIM_ + d]);
        acc[e] += xv.x * rv.x + xv.y * rv.y + xv.z * rv.z + xv.w * rv.w;
      }
    }
#pragma unroll
    for (int e = 0; e < 8; ++e)
#pragma unroll
      for (int off = 32; off; off >>= 1)
        acc[e] += __shfl_xor(acc[e], off, 64);
    if (lane == 0) {
      float v[8];
#pragma unroll
      for (int e = 0; e < 8; ++e) v[e] = acc[e] + sb[e];
      int i0 = 0;
#pragma unroll
      for (int e = 1; e < 8; ++e) if (v[e] > v[i0]) i0 = e;
      int i1 = (i0 == 0) ? 1 : 0;
#pragma unroll
      for (int e = 0; e < 8; ++e) if (e != i0 && v[e] > v[i1]) i1 = e;
      float w0 = 1.f / (1.f + expf(v[i1] - v[i0]));
      float w1 = 1.f - w0;
      int l0 = atomicAdd(&hcnt[i0], 1);
      int l1 = atomicAdd(&hcnt[i1], 1);
      te[lt * 2 + 0] = i0; twt[lt * 2 + 0] = w0; tloc[lt * 2 + 0] = l0;
      te[lt * 2 + 1] = i1; twt[lt * 2 + 1] = w1; tloc[lt * 2 + 1] = l1;
    }
  }
  __syncthreads();
  if (tid < E_) hbase[tid] = atomicAdd(&counts[tid], hcnt[tid]);
  __syncthreads();
  if (tid < RTOK * 2) {
    int e = te[tid];
    int p = hbase[e] + tloc[tid];
    int t = blockIdx.x * RTOK + (tid >> 1);
    btok[e * NTOK + p] = t;
    bw[e * NTOK + p] = twt[tid];
    tokrec[t * 2 + (tid & 1)] = (e << 13) | p;
  }
}

// ================= 256x256 GEMM core: dbuf, 1 barrier/K-tile =================
// 512 thr = 8 waves (2M x 4N), BK=64, 128 KiB LDS (2 bufs x [A 32K | B 32K]).
// Tile t reads buf[t&1]; tile t+1's 8 loads issue spread over t's 4 quarters
// into buf[(t+1)&1] (readers done >=1 barrier ago -> race-free). One
// vmcnt(0)+s_barrier at the tile boundary; in-flight depth = in-tile issue.
// Phase q computes m-quarter {2q,2q+1} x all n (16 MFMA): liveness/phase =
// 4 A-frags; B (8 frags, 32 VGPR) loaded once per tile; acc -> AGPR.

#define STG2(sm_, pArr, buf, reg, half, tile, NTt)                         \
  {                                                                        \
    int tc_ = (tile) < (NTt) ? (tile) : (NTt)-1;                           \
    u16* d_ = (sm_) + (buf)*32768 + (reg)*16384 + (half)*8192 + wid * 512; \
    gload16(pArr[(half)*2 + 0] + tc_ * 64, d_);                            \
    gload16(pArr[(half)*2 + 1] + tc_ * 64, d_ + 4096);                     \
  }

template <int NTt>
__device__ __forceinline__ void kloop(u16* __restrict__ sm,
                                      const u16* const* pA, const u16* const* pB,
                                      int wid, int wr, int wc, int l15, int lhi,
                                      int rxor, f32x4 (&acc)[8][4]) {
  // prologue: tile 0 -> buf0 (8 loads), full drain
  STG2(sm, pA, 0, 0, 0, 0, NTt); STG2(sm, pA, 0, 0, 1, 0, NTt);
  STG2(sm, pB, 0, 1, 0, 0, NTt); STG2(sm, pB, 0, 1, 1, 0, NTt);
  asm volatile("s_waitcnt vmcnt(0)" ::: "memory");
  __builtin_amdgcn_s_barrier();

  const uint32_t k0 = (uint32_t)(((lhi * 8) ^ rxor) * 2);        // byte offs
  const uint32_t k1 = (uint32_t)((((4 + lhi) * 8) ^ rxor) * 2);
  const uint32_t base = lds_addr(sm);

  for (int t = 0; t < NTt; ++t) {
    int cur = t & 1, nb = (t + 1) & 1;
    uint32_t aB = base + (uint32_t)(cur * 65536) + (uint32_t)((wr * 128 + l15) * 128);
    uint32_t bB = base + (uint32_t)(cur * 65536 + 32768) + (uint32_t)((wc * 64 + l15) * 128);

    // B fragments for the whole tile (8 reads, 32 VGPR live)
    bf16x8 b[4][2];
#pragma unroll
    for (int n = 0; n < 4; ++n) {
      b[n][0] = ldsr(bB + (uint32_t)(n * 2048) + k0);
      b[n][1] = ldsr(bB + (uint32_t)(n * 2048) + k1);
    }

#pragma unroll
    for (int q = 0; q < 4; ++q) {
      bf16x8 a[2][2];
#pragma unroll
      for (int m = 0; m < 2; ++m) {
        a[m][0] = ldsr(aB + (uint32_t)((q * 2 + m) * 2048) + k0);
        a[m][1] = ldsr(aB + (uint32_t)((q * 2 + m) * 2048) + k1);
      }
      // stage one half-tile of tile t+1 into the other buffer
      if (q == 0)      STG2(sm, pB, nb, 1, 0, t + 1, NTt)
      else if (q == 1) STG2(sm, pB, nb, 1, 1, t + 1, NTt)
      else if (q == 2) STG2(sm, pA, nb, 0, 0, t + 1, NTt)
      else             STG2(sm, pA, nb, 0, 1, t + 1, NTt)
      asm volatile("s_waitcnt lgkmcnt(0)");
      SB0;
      __builtin_amdgcn_s_setprio(1);
#pragma unroll
      for (int m = 0; m < 2; ++m)
#pragma unroll
        for (int n = 0; n < 4; ++n) {
          acc[q * 2 + m][n] = MFMA_(a[m][0], b[n][0], acc[q * 2 + m][n], 0, 0, 0);
          acc[q * 2 + m][n] = MFMA_(a[m][1], b[n][1], acc[q * 2 + m][n], 0, 0, 0);
        }
      __builtin_amdgcn_s_setprio(0);
    }
    // boundary: tile t+1's loads must have landed before next reads
    asm volatile("s_waitcnt vmcnt(0)" ::: "memory");
    __builtin_amdgcn_s_barrier();
  }
}

// ---------------- GEMM1: gathered x @ W1 -> swiglu -> hb ----------------

__launch_bounds__(512, 2)
__global__ void gemm1(const u16* __restrict__ xb, const u16* __restrict__ w1t,
                      const float* __restrict__ b1, const int* __restrict__ counts,
                      const int* __restrict__ btok, u16* __restrict__ hb) {
  int e = blockIdx.z, mblk = blockIdx.y, nblk = blockIdx.x;
  int cnt = counts[e];
  if (mblk * 256 >= cnt) return;
  int base = 0;
#pragma unroll
  for (int i = 0; i < 8; ++i) base += (i < e) ? counts[i] : 0;

  __shared__ u16 sm[65536];
  __shared__ int sTok[256];

  int tid = threadIdx.x, wid = tid >> 6, lane = tid & 63;
  if (tid < 256) {
    int gr = mblk * 256 + tid;
    sTok[tid] = (gr < cnt) ? btok[e * NTOK + gr] : btok[e * NTOK];
  }
  __syncthreads();

  int wr = wid >> 2, wc = wid & 3;
  int l15 = lane & 15, lhi = lane >> 4;
  int rxor = (l15 & 7) * 8;
  int segsw = ((tid & 7) ^ ((tid >> 3) & 7)) * 8;
  int rowi = tid >> 3;

  const u16* pA[4];
  const u16* pB[4];
  const size_t w1e = (size_t)e * H2_ * DIM_;
#pragma unroll
  for (int j = 0; j < 4; ++j) {
    int r = j * 64 + rowi;
    pA[j] = xb + (size_t)sTok[r] * DIM_ + segsw;
    int gcol = nblk * 128 + j * 32 + (rowi & 31) + ((rowi >> 5) & 1) * 2048;
    pB[j] = w1t + w1e + (size_t)gcol * DIM_ + segsw;
  }

  f32x4 acc[8][4] = {};
  kloop<NT1>(sm, pA, pB, wid, wr, wc, l15, lhi, rxor, acc);

#pragma unroll
  for (int q = 0; q < 2; ++q) {
    int oc = nblk * 128 + wc * 32 + q * 16 + l15;
    float bb1 = b1[e * H2_ + oc];
    float bb2 = b1[e * H2_ + oc + HID_];
#pragma unroll
    for (int m = 0; m < 8; ++m) {
#pragma unroll
      for (int j = 0; j < 4; ++j) {
        int rt = wr * 128 + m * 16 + lhi * 4 + j;
        int gr = mblk * 256 + rt;
        if (gr < cnt) {
          float h1 = acc[m][q][j] + bb1;
          float h2 = acc[m][q + 2][j] + bb2;
          float s = (h1 / (1.f + __expf(-h1))) * h2;
          hb[(size_t)(base + gr) * HID_ + oc] = f2bf(s);
        }
      }
    }
  }
}

// ---------------- GEMM2: hb @ W2 -> w*(y+b2) stored bf16 to ybuf ----------------

__launch_bounds__(512, 2)
__global__ void gemm2(const u16* __restrict__ hb, const u16* __restrict__ w2t,
                      const float* __restrict__ b2, const int* __restrict__ counts,
                      const float* __restrict__ bw, u16* __restrict__ ybuf) {
  int e = blockIdx.z, mblk = blockIdx.y, nblk = blockIdx.x;
  int cnt = counts[e];
  if (mblk * 256 >= cnt) return;
  int base = 0;
#pragma unroll
  for (int i = 0; i < 8; ++i) base += (i < e) ? counts[i] : 0;

  __shared__ u16 sm[65536];
  __shared__ float sW[256];

  int tid = threadIdx.x, wid = tid >> 6, lane = tid & 63;
  if (tid < 256) {
    int gr = mblk * 256 + tid;
    sW[tid] = (gr < cnt) ? bw[e * NTOK + gr] : 0.f;
  }
  __syncthreads();

  int wr = wid >> 2, wc = wid & 3;
  int l15 = lane & 15, lhi = lane >> 4;
  int rxor = (l15 & 7) * 8;
  int segsw = ((tid & 7) ^ ((tid >> 3) & 7)) * 8;
  int rowi = tid >> 3;

  const u16* pA[4];
  const u16* pB[4];
#pragma unroll
  for (int j = 0; j < 4; ++j) {
    pA[j] = hb + (size_t)(base + mblk * 256 + j * 64 + rowi) * HID_ + segsw;
    pB[j] = w2t + (size_t)e * DIM_ * HID_ +
            (size_t)(nblk * 256 + j * 64 + rowi) * HID_ + segsw;
  }

  f32x4 acc[8][4] = {};
  kloop<NT2>(sm, pA, pB, wid, wr, wc, l15, lhi, rxor, acc);

#pragma unroll
  for (int q = 0; q < 4; ++q) {
    int col = nblk * 256 + wc * 64 + q * 16 + l15;
    float bb = b2[e * DIM_ + col];
#pragma unroll
    for (int m = 0; m < 8; ++m) {
#pragma unroll
      for (int j = 0; j < 4; ++j) {
        int rt = wr * 128 + m * 16 + lhi * 4 + j;
        int gr = mblk * 256 + rt;
        if (gr < cnt)
          ybuf[(size_t)(base + gr) * DIM_ + col] = f2bf(sW[rt] * (acc[m][q][j] + bb));
      }
    }
  }
}

// ---------------- combine: out[t] = ybuf[slot(t,0)] + ybuf[slot(t,1)] ----------------

__global__ void combine(const u16* __restrict__ ybuf, const int* __restrict__ tokrec,
                        const int* __restrict__ counts, float* __restrict__ out) {
  __shared__ int sbase[8];
  int tid = threadIdx.x;
  if (tid == 0) {
    int b = 0;
#pragma unroll
    for (int e = 0; e < 8; ++e) { sbase[e] = b; b += counts[e]; }
  }
  __syncthreads();
  int t = blockIdx.x;
  int r0 = tokrec[t * 2 + 0], r1 = tokrec[t * 2 + 1];
  size_t s0 = (size_t)(sbase[r0 >> 13] + (r0 & 8191)) * DIM_;
  size_t s1 = (size_t)(sbase[r1 >> 13] + (r1 & 8191)) * DIM_;
  int c = tid * 4;
  ushort4 a = *(const ushort4*)(ybuf + s0 + c);
  ushort4 b = *(const ushort4*)(ybuf + s1 + c);
  float4 o;
  o.x = bf2f(a.x) + bf2f(b.x);
  o.y = bf2f(a.y) + bf2f(b.y);
  o.z = bf2f(a.z) + bf2f(b.z);
  o.w = bf2f(a.w) + bf2f(b.w);
  *(float4*)(out + (size_t)t * DIM_ + c) = o;
}

// ---------------- launch ----------------

extern "C" void kernel_launch(void* const* d_in, const int* in_sizes, int n_in,
                              void* d_out, int out_size, void* d_ws, size_t ws_size,
                              hipStream_t stream) {
  const float* x  = (const float*)d_in[0];
  const float* rw = (const float*)d_in[1];
  const float* rb = (const float*)d_in[2];
  const float* W1 = (const float*)d_in[3];
  const float* b1 = (const float*)d_in[4];
  const float* W2 = (const float*)d_in[5];
  const float* b2 = (const float*)d_in[6];
  float* out = (float*)d_out;

  char* ws = (char*)d_ws;
  int*   counts = (int*)ws;                         // 32 B (256 pad)
  int*   btok   = (int*)(ws + 256);                 // 256 KB
  float* bw     = (float*)(ws + 256 + 262144);      // 256 KB
  int*   tokrec = (int*)(ws + 256 + 524288);        // 64 KB
  u16* xb  = (u16*)(ws + (1u << 20));               // 16 MB
  u16* w1t = xb  + (size_t)NTOK * DIM_;             // 64 MB
  u16* w2t = w1t + (size_t)E_ * H2_ * DIM_;         // 32 MB
  u16* hb  = w2t + (size_t)E_ * DIM_ * HID_;        // (16384+256)*2048*2 B
  u16* ybuf = w1t;  // alias: w1t dead after gemm1

  hipMemsetAsync(counts, 0, 8 * sizeof(int), stream);

  cvt_x<<<(NTOK * DIM_ / 8 + 255) / 256, 256, 0, stream>>>(x, xb, NTOK * DIM_ / 8);
  tconv<<<dim3(H2_ / 64, DIM_ / 64, E_), 256, 0, stream>>>(W1, w1t, DIM_, H2_);
  tconv<<<dim3(DIM_ / 64, HID_ / 64, E_), 256, 0, stream>>>(W2, w2t, HID_, DIM_);
  router<<<NTOK / RTOK, 256, 0, stream>>>(x, rw, rb, counts, btok, bw, tokrec);

  gemm1<<<dim3(H2_ / 256, NTOK / 256, E_), 512, 0, stream>>>(xb, w1t, b1, counts, btok, hb);
  gemm2<<<dim3(DIM_ / 256, NTOK / 256, E_), 512, 0, stream>>>(hb, w2t, b2, counts, bw, ybuf);
  combine<<<NTOK, 256, 0, stream>>>(ybuf, tokrec, counts, out);
}

// Round 9
// 401.652 us; speedup vs baseline: 2.0538x; 1.1151x over previous
//
#include <hip/hip_runtime.h>
#include <stdint.h>

typedef unsigned short u16;

#define E_    8
#define DIM_  1024
#define HID_  2048
#define H2_   4096     // 2*HID
#define NTOK  8192     // B*T
#define RTOK  32       // tokens per router block

typedef __attribute__((ext_vector_type(8))) short bf16x8;
typedef __attribute__((ext_vector_type(4))) float f32x4;

__device__ __forceinline__ u16 f2bf(float f) {
  uint32_t u = __builtin_bit_cast(uint32_t, f);
  uint32_t r = (u + 0x7FFFu + ((u >> 16) & 1u)) >> 16;
  return (u16)r;
}
__device__ __forceinline__ float bf2f(u16 u) {
  return __builtin_bit_cast(float, (uint32_t)u << 16);
}

__device__ __forceinline__ void gload16(const void* g, void* l) {
  __builtin_amdgcn_global_load_lds(
      (const __attribute__((address_space(1))) void*)g,
      (__attribute__((address_space(3))) void*)l, 16, 0, 0);
}

// ---------------- conversion kernels ----------------

__global__ void cvt_x(const float* __restrict__ x, u16* __restrict__ xb, int n8) {
  int i = blockIdx.x * blockDim.x + threadIdx.x;
  if (i >= n8) return;
  const float4* p = (const float4*)(x + (size_t)i * 8);
  float4 a = p[0], b = p[1];
  union { u16 u[8]; uint4 v; } r;
  r.u[0] = f2bf(a.x); r.u[1] = f2bf(a.y); r.u[2] = f2bf(a.z); r.u[3] = f2bf(a.w);
  r.u[4] = f2bf(b.x); r.u[5] = f2bf(b.y); r.u[6] = f2bf(b.z); r.u[7] = f2bf(b.w);
  *(uint4*)(xb + (size_t)i * 8) = r.v;
}

// src [e][R][C] fp32 -> dst [e][C][R] bf16 (64x64 tiles, 128B write granule)
__global__ void tconv(const float* __restrict__ src, u16* __restrict__ dst, int R, int C) {
  __shared__ float t[64][65];
  int e = blockIdx.z;
  int r0 = blockIdx.y * 64, c0 = blockIdx.x * 64;
  const float* s = src + (size_t)e * R * C;
  u16* d = dst + (size_t)e * R * C;
  int tid = threadIdx.x;
  int rr = tid >> 4, cc = (tid & 15) * 4;
#pragma unroll
  for (int p = 0; p < 4; ++p) {
    float4 v = *(const float4*)(s + (size_t)(r0 + p * 16 + rr) * C + c0 + cc);
    t[p * 16 + rr][cc + 0] = v.x; t[p * 16 + rr][cc + 1] = v.y;
    t[p * 16 + rr][cc + 2] = v.z; t[p * 16 + rr][cc + 3] = v.w;
  }
  __syncthreads();
  int cr = tid >> 3, rc = (tid & 7) * 8;
#pragma unroll
  for (int p = 0; p < 2; ++p) {
    union { u16 u[8]; uint4 v; } w;
#pragma unroll
    for (int j = 0; j < 8; ++j) w.u[j] = f2bf(t[rc + j][p * 32 + cr]);
    *(uint4*)(d + (size_t)(c0 + p * 32 + cr) * R + r0 + rc) = w.v;
  }
}

// ---------------- router (block-aggregated, low-contention atomics) ----------------

__global__ void router(const float* __restrict__ x, const float* __restrict__ rw,
                       const float* __restrict__ rb, int* __restrict__ counts,
                       int* __restrict__ btok, float* __restrict__ bw,
                       int* __restrict__ tokrec) {
  __shared__ float srw[E_ * DIM_];
  __shared__ float sb[E_];
  __shared__ int   hcnt[E_], hbase[E_];
  __shared__ int   te[RTOK * 2];
  __shared__ float twt[RTOK * 2];
  __shared__ int   tloc[RTOK * 2];

  int tid = threadIdx.x;
  for (int i = tid; i < E_ * DIM_ / 4; i += 256)
    ((float4*)srw)[i] = ((const float4*)rw)[i];
  if (tid < E_) { sb[tid] = rb[tid]; hcnt[tid] = 0; }
  __syncthreads();

  int wid = tid >> 6, lane = tid & 63;
#pragma unroll
  for (int s = 0; s < RTOK / 4; ++s) {
    int lt = wid * (RTOK / 4) + s;
    int t = blockIdx.x * RTOK + lt;
    const float* xt = x + (size_t)t * DIM_;
    float acc[8] = {0.f, 0.f, 0.f, 0.f, 0.f, 0.f, 0.f, 0.f};
#pragma unroll
    for (int it = 0; it < 4; ++it) {
      int d = it * 256 + lane * 4;
      float4 xv = *(const float4*)(xt + d);
#pragma unroll
      for (int e = 0; e < 8; ++e) {
        float4 rv = *(const float4*)(&srw[e * DIM_ + d]);
        acc[e] += xv.x * rv.x + xv.y * rv.y + xv.z * rv.z + xv.w * rv.w;
      }
    }
#pragma unroll
    for (int e = 0; e < 8; ++e)
#pragma unroll
      for (int off = 32; off; off >>= 1)
        acc[e] += __shfl_xor(acc[e], off, 64);
    if (lane == 0) {
      float v[8];
#pragma unroll
      for (int e = 0; e < 8; ++e) v[e] = acc[e] + sb[e];
      int i0 = 0;
#pragma unroll
      for (int e = 1; e < 8; ++e) if (v[e] > v[i0]) i0 = e;
      int i1 = (i0 == 0) ? 1 : 0;
#pragma unroll
      for (int e = 0; e < 8; ++e) if (e != i0 && v[e] > v[i1]) i1 = e;
      float w0 = 1.f / (1.f + expf(v[i1] - v[i0]));
      float w1 = 1.f - w0;
      int l0 = atomicAdd(&hcnt[i0], 1);
      int l1 = atomicAdd(&hcnt[i1], 1);
      te[lt * 2 + 0] = i0; twt[lt * 2 + 0] = w0; tloc[lt * 2 + 0] = l0;
      te[lt * 2 + 1] = i1; twt[lt * 2 + 1] = w1; tloc[lt * 2 + 1] = l1;
    }
  }
  __syncthreads();
  if (tid < E_) hbase[tid] = atomicAdd(&counts[tid], hcnt[tid]);
  __syncthreads();
  if (tid < RTOK * 2) {
    int e = te[tid];
    int p = hbase[e] + tloc[tid];
    int t = blockIdx.x * RTOK + (tid >> 1);
    btok[e * NTOK + p] = t;
    bw[e * NTOK + p] = twt[tid];
    tokrec[t * 2 + (tid & 1)] = (e << 13) | p;
  }
}

// ---------------- GEMM1: gathered x @ W1 -> swiglu -> hb ----------------
// 128x128 tile, BK=64, XOR-swizzled LDS (R5-proven), 4 blocks/CU.

__launch_bounds__(256, 4)
__global__ void gemm1(const u16* __restrict__ xb, const u16* __restrict__ w1t,
                      const float* __restrict__ b1, const int* __restrict__ counts,
                      const int* __restrict__ btok, u16* __restrict__ hb) {
  int e = blockIdx.z, mblk = blockIdx.y, nblk = blockIdx.x;
  int cnt = counts[e];
  if (mblk * 128 >= cnt) return;
  int base = 0;
#pragma unroll
  for (int i = 0; i < 8; ++i) base += (i < e) ? counts[i] : 0;

  __shared__ u16 lA[128 * 64];
  __shared__ u16 lB[128 * 64];
  __shared__ int sTok[128];

  int tid = threadIdx.x, wid = tid >> 6, lane = tid & 63;
  if (tid < 128) {
    int gr = mblk * 128 + tid;
    sTok[tid] = (gr < cnt) ? btok[e * NTOK + gr] : btok[e * NTOK];
  }
  __syncthreads();

  f32x4 acc[4][4] = {};
  int wr = wid >> 1, wc = wid & 1;
  int l15 = lane & 15, lhi = lane >> 4;
  const size_t w1e = (size_t)e * H2_ * DIM_;

  int segsw = ((lane & 7) ^ ((lane >> 3) & 7)) * 8;
  const u16* gA[4];
  const u16* gB[4];
#pragma unroll
  for (int i = 0; i < 4; ++i) {
    int r = wid * 32 + i * 8 + (lane >> 3);
    gA[i] = xb + (size_t)sTok[r] * DIM_ + segsw;
    int gcol = nblk * 64 + (r >> 6) * 32 + (r & 31) + ((r >> 5) & 1) * 2048;
    gB[i] = w1t + w1e + (size_t)gcol * DIM_ + segsw;
  }
  int rxor = (l15 & 7) * 8;

  for (int kt = 0; kt < DIM_ / 64; ++kt) {
#pragma unroll
    for (int i = 0; i < 4; ++i)
      gload16(gA[i] + kt * 64, &lA[(wid * 32 + i * 8) * 64]);
#pragma unroll
    for (int i = 0; i < 4; ++i)
      gload16(gB[i] + kt * 64, &lB[(wid * 32 + i * 8) * 64]);
    __syncthreads();
#pragma unroll
    for (int ks = 0; ks < 2; ++ks) {
      int segrd = ((ks * 4 + lhi) * 8) ^ rxor;
      bf16x8 a[4], b[4];
#pragma unroll
      for (int m = 0; m < 4; ++m)
        a[m] = *(const bf16x8*)&lA[(wr * 64 + m * 16 + l15) * 64 + segrd];
#pragma unroll
      for (int n = 0; n < 4; ++n)
        b[n] = *(const bf16x8*)&lB[(wc * 64 + n * 16 + l15) * 64 + segrd];
#pragma unroll
      for (int m = 0; m < 4; ++m)
#pragma unroll
        for (int n = 0; n < 4; ++n)
          acc[m][n] = __builtin_amdgcn_mfma_f32_16x16x32_bf16(a[m], b[n], acc[m][n], 0, 0, 0);
    }
    __syncthreads();
  }

#pragma unroll
  for (int n = 0; n < 2; ++n) {
    int outcol = nblk * 64 + wc * 32 + n * 16 + l15;
    float bb1 = b1[e * H2_ + outcol];
    float bb2 = b1[e * H2_ + outcol + HID_];
#pragma unroll
    for (int m = 0; m < 4; ++m) {
#pragma unroll
      for (int j = 0; j < 4; ++j) {
        int rt = wr * 64 + m * 16 + lhi * 4 + j;
        int gr = mblk * 128 + rt;
        if (gr < cnt) {
          float h1 = acc[m][n][j] + bb1;
          float h2 = acc[m][n + 2][j] + bb2;
          float s = (h1 / (1.f + __expf(-h1))) * h2;
          hb[(size_t)(base + gr) * HID_ + outcol] = f2bf(s);
        }
      }
    }
  }
}

// ---------------- GEMM2: hb @ W2 -> w*(y+b2) stored bf16 to ybuf ----------------

__launch_bounds__(256, 4)
__global__ void gemm2(const u16* __restrict__ hb, const u16* __restrict__ w2t,
                      const float* __restrict__ b2, const int* __restrict__ counts,
                      const float* __restrict__ bw, u16* __restrict__ ybuf) {
  int e = blockIdx.z, mblk = blockIdx.y, nblk = blockIdx.x;
  int cnt = counts[e];
  if (mblk * 128 >= cnt) return;
  int base = 0;
#pragma unroll
  for (int i = 0; i < 8; ++i) base += (i < e) ? counts[i] : 0;

  __shared__ u16 lA[128 * 64];
  __shared__ u16 lB[128 * 64];
  __shared__ float sW[128];

  int tid = threadIdx.x, wid = tid >> 6, lane = tid & 63;
  if (tid < 128) {
    int gr = mblk * 128 + tid;
    sW[tid] = (gr < cnt) ? bw[e * NTOK + gr] : 0.f;
  }
  __syncthreads();

  f32x4 acc[4][4] = {};
  int wr = wid >> 1, wc = wid & 1;
  int l15 = lane & 15, lhi = lane >> 4;

  int segsw = ((lane & 7) ^ ((lane >> 3) & 7)) * 8;
  const u16* gA[4];
  const u16* gB[4];
#pragma unroll
  for (int i = 0; i < 4; ++i) {
    int r = wid * 32 + i * 8 + (lane >> 3);
    gA[i] = hb + (size_t)(base + mblk * 128 + r) * HID_ + segsw;
    gB[i] = w2t + (size_t)e * DIM_ * HID_ + (size_t)(nblk * 128 + r) * HID_ + segsw;
  }
  int rxor = (l15 & 7) * 8;

  for (int kt = 0; kt < HID_ / 64; ++kt) {
#pragma unroll
    for (int i = 0; i < 4; ++i) {
      gload16(gA[i] + kt * 64, &lA[(wid * 32 + i * 8) * 64]);
      gload16(gB[i] + kt * 64, &lB[(wid * 32 + i * 8) * 64]);
    }
    __syncthreads();
#pragma unroll
    for (int ks = 0; ks < 2; ++ks) {
      int segrd = ((ks * 4 + lhi) * 8) ^ rxor;
      bf16x8 a[4], b[4];
#pragma unroll
      for (int m = 0; m < 4; ++m)
        a[m] = *(const bf16x8*)&lA[(wr * 64 + m * 16 + l15) * 64 + segrd];
#pragma unroll
      for (int n = 0; n < 4; ++n)
        b[n] = *(const bf16x8*)&lB[(wc * 64 + n * 16 + l15) * 64 + segrd];
#pragma unroll
      for (int m = 0; m < 4; ++m)
#pragma unroll
        for (int n = 0; n < 4; ++n)
          acc[m][n] = __builtin_amdgcn_mfma_f32_16x16x32_bf16(a[m], b[n], acc[m][n], 0, 0, 0);
    }
    __syncthreads();
  }

#pragma unroll
  for (int n = 0; n < 4; ++n) {
    int col = nblk * 128 + wc * 64 + n * 16 + l15;
    float bb = b2[e * DIM_ + col];
#pragma unroll
    for (int m = 0; m < 4; ++m) {
#pragma unroll
      for (int j = 0; j < 4; ++j) {
        int rt = wr * 64 + m * 16 + lhi * 4 + j;
        int gr = mblk * 128 + rt;
        if (gr < cnt)
          ybuf[(size_t)(base + gr) * DIM_ + col] = f2bf(sW[rt] * (acc[m][n][j] + bb));
      }
    }
  }
}

// ---------------- combine: out[t] = ybuf[slot(t,0)] + ybuf[slot(t,1)] ----------------

__global__ void combine(const u16* __restrict__ ybuf, const int* __restrict__ tokrec,
                        const int* __restrict__ counts, float* __restrict__ out) {
  __shared__ int sbase[8];
  int tid = threadIdx.x;
  if (tid == 0) {
    int b = 0;
#pragma unroll
    for (int e = 0; e < 8; ++e) { sbase[e] = b; b += counts[e]; }
  }
  __syncthreads();
  int t = blockIdx.x;
  int r0 = tokrec[t * 2 + 0], r1 = tokrec[t * 2 + 1];
  size_t s0 = (size_t)(sbase[r0 >> 13] + (r0 & 8191)) * DIM_;
  size_t s1 = (size_t)(sbase[r1 >> 13] + (r1 & 8191)) * DIM_;
  int c = tid * 4;
  ushort4 a = *(const ushort4*)(ybuf + s0 + c);
  ushort4 b = *(const ushort4*)(ybuf + s1 + c);
  float4 o;
  o.x = bf2f(a.x) + bf2f(b.x);
  o.y = bf2f(a.y) + bf2f(b.y);
  o.z = bf2f(a.z) + bf2f(b.z);
  o.w = bf2f(a.w) + bf2f(b.w);
  *(float4*)(out + (size_t)t * DIM_ + c) = o;
}

// ---------------- launch ----------------

extern "C" void kernel_launch(void* const* d_in, const int* in_sizes, int n_in,
                              void* d_out, int out_size, void* d_ws, size_t ws_size,
                              hipStream_t stream) {
  const float* x  = (const float*)d_in[0];
  const float* rw = (const float*)d_in[1];
  const float* rb = (const float*)d_in[2];
  const float* W1 = (const float*)d_in[3];
  const float* b1 = (const float*)d_in[4];
  const float* W2 = (const float*)d_in[5];
  const float* b2 = (const float*)d_in[6];
  float* out = (float*)d_out;

  char* ws = (char*)d_ws;
  int*   counts = (int*)ws;                         // 32 B (256 pad)
  int*   btok   = (int*)(ws + 256);                 // 256 KB
  float* bw     = (float*)(ws + 256 + 262144);      // 256 KB
  int*   tokrec = (int*)(ws + 256 + 524288);        // 64 KB
  u16* xb  = (u16*)(ws + (1u << 20));               // 16 MB
  u16* w1t = xb  + (size_t)NTOK * DIM_;             // 64 MB
  u16* w2t = w1t + (size_t)E_ * H2_ * DIM_;         // 32 MB
  u16* hb  = w2t + (size_t)E_ * DIM_ * HID_;        // (16384+128)*2048*2 B
  u16* ybuf = w1t;  // alias: w1t dead after gemm1

  hipMemsetAsync(counts, 0, 8 * sizeof(int), stream);

  cvt_x<<<(NTOK * DIM_ / 8 + 255) / 256, 256, 0, stream>>>(x, xb, NTOK * DIM_ / 8);
  tconv<<<dim3(H2_ / 64, DIM_ / 64, E_), 256, 0, stream>>>(W1, w1t, DIM_, H2_);
  tconv<<<dim3(DIM_ / 64, HID_ / 64, E_), 256, 0, stream>>>(W2, w2t, HID_, DIM_);
  router<<<NTOK / RTOK, 256, 0, stream>>>(x, rw, rb, counts, btok, bw, tokrec);

  gemm1<<<dim3(H2_ / 128, NTOK / 128, E_), 256, 0, stream>>>(xb, w1t, b1, counts, btok, hb);
  gemm2<<<dim3(DIM_ / 128, NTOK / 128, E_), 256, 0, stream>>>(hb, w2t, b2, counts, bw, ybuf);
  combine<<<NTOK, 256, 0, stream>>>(ybuf, tokrec, counts, out);
}